// Round 1
// baseline (397.000 us; speedup 1.0000x reference)
//
#include <hip/hip_runtime.h>

using u16 = unsigned short;
typedef __bf16 bf16x8 __attribute__((ext_vector_type(8)));
typedef float f32x4 __attribute__((ext_vector_type(4)));
typedef float f32x2 __attribute__((ext_vector_type(2)));

#define BM 128
#define BN 128
#define BK 32

// ---------------------------------------------------------------------------
// fp32 -> bf16 round-to-nearest-even (bit trick; NaN not expected here)
__device__ inline u16 f32_to_bf16_rne(float f) {
    unsigned u = __float_as_uint(f);
    u += 0x7FFFu + ((u >> 16) & 1u);
    return (u16)(u >> 16);
}

// async global->LDS, 16 bytes per lane. LDS dest must be wave-uniform base.
__device__ inline void async16(const void* g, void* l) {
    __builtin_amdgcn_global_load_lds(
        (__attribute__((address_space(1))) void*)(g),
        (__attribute__((address_space(3))) void*)(l),
        16, 0, 0);
}

// ---------------------------------------------------------------------------
// Quantize (per-128-block, scale = amax/448, fp8 e4m3fn RNE) then dequantize
// to bf16. One 64-lane wave per 128-element block; 4 waves per 256-thr block.
__global__ void qdq_kernel(const float* __restrict__ in, u16* __restrict__ out,
                           long nblk) {
    long wid = (long)blockIdx.x * 4 + (threadIdx.x >> 6);
    int lane = threadIdx.x & 63;
    if (wid >= nblk) return;

    float2 v = reinterpret_cast<const float2*>(in + wid * 128)[lane];
    float a = fmaxf(fabsf(v.x), fabsf(v.y));
#pragma unroll
    for (int off = 32; off; off >>= 1) a = fmaxf(a, __shfl_xor(a, off));

    float s = a / 448.0f;               // fp32 IEEE divide, matches jnp
    // true IEEE divides, matches reference's xb / s
    float qx = v.x / s;
    float qy = v.y / s;
    // clamp: insurance for div rounding pushing |q| one ulp past 448
    qx = fminf(fmaxf(qx, -448.0f), 448.0f);
    qy = fminf(fmaxf(qy, -448.0f), 448.0f);

    int pk = __builtin_amdgcn_cvt_pk_fp8_f32(qx, qy, 0, false); // RNE, OCP e4m3fn
    f32x2 d = __builtin_amdgcn_cvt_pk_f32_fp8(pk, false);

    ushort2 o;
    o.x = f32_to_bf16_rne(d.x * s);
    o.y = f32_to_bf16_rne(d.y * s);
    reinterpret_cast<ushort2*>(out + wid * 128)[lane] = o;
}

// ---------------------------------------------------------------------------
// bf16 GEMM, C[M,N] = A[M,K] * B[N,K]^T, fp32 accumulate.
// m97 structure: 128x128 tile, BK=32, 4 waves (2x2), 4x4 16x16x32 MFMA frags,
// global_load_lds width-16 staging, 2 barriers / K-step.
__global__ __launch_bounds__(256, 2) void gemm_bt(
    const u16* __restrict__ A, const u16* __restrict__ B,
    float* __restrict__ C, int M, int N, int K) {
    __shared__ __align__(16) u16 As[BM * BK];
    __shared__ __align__(16) u16 Bs[BN * BK];

    const int tid = threadIdx.x;
    const int wid = tid >> 6;
    const int lane = tid & 63;

    // XCD-aware bijective swizzle (grid % 8 == 0 here)
    int nwg = gridDim.x;
    int bid = blockIdx.x;
    int swz = bid;
    if ((nwg & 7) == 0) {
        int cpx = nwg >> 3;
        swz = (bid & 7) * cpx + (bid >> 3);
    }
    const int nbn = N / BN;
    const int brow = (swz / nbn) * BM;
    const int bcol = (swz % nbn) * BN;

    const int wr = wid >> 1, wc = wid & 1;

    f32x4 acc[4][4];
#pragma unroll
    for (int i = 0; i < 4; ++i)
#pragma unroll
        for (int j = 0; j < 4; ++j) acc[i][j] = (f32x4){0.f, 0.f, 0.f, 0.f};

    const long rowb = (long)K * 2;
    // staging: thread t loads 16B of row (t>>2), byte col (t&3)*16; 2 issues
    // per operand cover 128 rows. LDS linear => dest offset = t*16 (+4096).
    const char* Ag = (const char*)A + ((long)brow + (tid >> 2)) * rowb + (tid & 3) * 16;
    const char* Bg = (const char*)B + ((long)bcol + (tid >> 2)) * rowb + (tid & 3) * 16;
    char* AsD = (char*)As + wid * 1024;  // wave-uniform LDS base
    char* BsD = (char*)Bs + wid * 1024;

    const int fr = lane & 15;        // fragment row (A) / out col (B)
    const int fk = (lane >> 4) * 8;  // k element offset

    const int kiters = K / BK;
    for (int kt = 0; kt < kiters; ++kt) {
        const long koff = (long)kt * (BK * 2);
        async16(Ag + koff, AsD);
        async16(Ag + koff + 64 * rowb, AsD + 4096);
        async16(Bg + koff, BsD);
        async16(Bg + koff + 64 * rowb, BsD + 4096);
        __syncthreads();  // compiler emits vmcnt(0) drain before barrier

        bf16x8 af[4], bfr[4];
#pragma unroll
        for (int mi = 0; mi < 4; ++mi)
            af[mi] = *reinterpret_cast<const bf16x8*>(
                &As[(wr * 64 + mi * 16 + fr) * BK + fk]);
#pragma unroll
        for (int ni = 0; ni < 4; ++ni)
            bfr[ni] = *reinterpret_cast<const bf16x8*>(
                &Bs[(wc * 64 + ni * 16 + fr) * BK + fk]);
#pragma unroll
        for (int mi = 0; mi < 4; ++mi)
#pragma unroll
            for (int ni = 0; ni < 4; ++ni)
                acc[mi][ni] = __builtin_amdgcn_mfma_f32_16x16x32_bf16(
                    af[mi], bfr[ni], acc[mi][ni], 0, 0, 0);
        __syncthreads();
    }

    // epilogue: C/D layout col = lane&15, row = (lane>>4)*4 + reg
    const int crow0 = brow + wr * 64 + (lane >> 4) * 4;
    const int ccol0 = bcol + wc * 64 + fr;
#pragma unroll
    for (int mi = 0; mi < 4; ++mi)
#pragma unroll
        for (int ni = 0; ni < 4; ++ni)
#pragma unroll
            for (int j = 0; j < 4; ++j) {
                long r = crow0 + mi * 16 + j;
                C[r * (long)N + ccol0 + ni * 16] = acc[mi][ni][j];
            }
}

// ---------------------------------------------------------------------------
extern "C" void kernel_launch(void* const* d_in, const int* in_sizes, int n_in,
                              void* d_out, int out_size, void* d_ws, size_t ws_size,
                              hipStream_t stream) {
    const float* x = (const float*)d_in[0];   // [B,T,D] fp32, M = B*T
    const float* w = (const float*)d_in[1];   // [O,D] fp32
    float* out = (float*)d_out;               // [M,O] fp32

    const int K = 4096;
    const long M = (long)in_sizes[0] / K;     // 8192
    const long N = (long)in_sizes[1] / K;     // 4096

    u16* Adq = (u16*)d_ws;                    // [M,K] bf16 dequantized x
    u16* Bdq = Adq + (size_t)M * K;           // [N,K] bf16 dequantized w

    const long nblkA = M * (K / 128);
    const long nblkB = N * (K / 128);
    qdq_kernel<<<dim3((unsigned)((nblkA + 3) / 4)), dim3(256), 0, stream>>>(x, Adq, nblkA);
    qdq_kernel<<<dim3((unsigned)((nblkB + 3) / 4)), dim3(256), 0, stream>>>(w, Bdq, nblkB);

    dim3 grid((unsigned)((M / BM) * (N / BN)));
    gemm_bt<<<grid, dim3(256), 0, stream>>>(Adq, Bdq, out, (int)M, (int)N, K);
}

// Round 2
// 329.772 us; speedup vs baseline: 1.2039x; 1.2039x over previous
//
#include <hip/hip_runtime.h>

using u16 = unsigned short;
typedef __bf16 bf16x8 __attribute__((ext_vector_type(8)));
typedef float f32x4 __attribute__((ext_vector_type(4)));
typedef float f32x2 __attribute__((ext_vector_type(2)));

// ---------------------------------------------------------------------------
__device__ inline u16 f32_to_bf16_rne(float f) {
    unsigned u = __float_as_uint(f);
    u += 0x7FFFu + ((u >> 16) & 1u);
    return (u16)(u >> 16);
}

__device__ inline void async16(const void* g, void* l) {
    __builtin_amdgcn_global_load_lds(
        (__attribute__((address_space(1))) void*)(g),
        (__attribute__((address_space(3))) void*)(l),
        16, 0, 0);
}

// ---------------------------------------------------------------------------
// Quantize (per-128-block, scale = amax/448, fp8 e4m3fn RNE) then dequantize
// to bf16. One 64-lane wave per 128-element block. (HBM roofline: ~6.1 TB/s.)
__global__ void qdq_kernel(const float* __restrict__ in, u16* __restrict__ out,
                           long nblk) {
    long wid = (long)blockIdx.x * 4 + (threadIdx.x >> 6);
    int lane = threadIdx.x & 63;
    if (wid >= nblk) return;

    float2 v = reinterpret_cast<const float2*>(in + wid * 128)[lane];
    float a = fmaxf(fabsf(v.x), fabsf(v.y));
#pragma unroll
    for (int off = 32; off; off >>= 1) a = fmaxf(a, __shfl_xor(a, off));

    float s = a / 448.0f;
    float qx = v.x / s;
    float qy = v.y / s;
    qx = fminf(fmaxf(qx, -448.0f), 448.0f);
    qy = fminf(fmaxf(qy, -448.0f), 448.0f);

    int pk = __builtin_amdgcn_cvt_pk_fp8_f32(qx, qy, 0, false);
    f32x2 d = __builtin_amdgcn_cvt_pk_f32_fp8(pk, false);

    ushort2 o;
    o.x = f32_to_bf16_rne(d.x * s);
    o.y = f32_to_bf16_rne(d.y * s);
    reinterpret_cast<ushort2*>(out + wid * 128)[lane] = o;
}

// ---------------------------------------------------------------------------
// bf16 GEMM C[M,N] = A[M,K]*B[N,K]^T, fp32 acc. 256x256 8-phase template:
// BK=64, 8 waves (2x4), 128KiB LDS dbuf, st_16x32 swizzle, counted vmcnt,
// setprio around MFMA clusters. Halves per K-tile (consumption order):
//   j0: A-sec0 (rows [0,64)u[128,192))   j1: B-sec0 (rows ==0..31 mod 64)
//   j2: B-sec1                           j3: A-sec1
// Phases per tile (quadrant Gray order):
//   tp1: read A0+B0 (12), stage h=4T+5, MFMA(m0,n0)
//   tp2: read B1 (4),     stage h=4T+6, MFMA(m0,n1)
//   tp3: read A1 (8),     stage h=4T+7, MFMA(m1,n1)
//   tp4: read none,       stage h=4T+8, MFMA(m1,n0)
// vmcnt(6) at end of every phase => all but newest 3 halves landed.

#define SWZ(x) ((x) ^ ((((x) >> 9) & 1) << 5))

#define STAGE0(Th) { int b_=(Th)&1; char* d_=smem + b_*32768 + wid*1024; \
    long ko_=(long)(Th)*128; \
    async16(src00+ko_, d_); async16(src01+ko_, d_+8192); }
#define STAGE1(Th) { int b_=(Th)&1; char* d_=smem + 65536 + b_*32768 + wid*1024; \
    long ko_=(long)(Th)*128; \
    async16(src10+ko_, d_); async16(src11+ko_, d_+8192); }
#define STAGE2(Th) { int b_=(Th)&1; char* d_=smem + 65536 + b_*32768 + 16384 + wid*1024; \
    long ko_=(long)(Th)*128; \
    async16(src20+ko_, d_); async16(src21+ko_, d_+8192); }
#define STAGE3(Th) { int b_=(Th)&1; char* d_=smem + b_*32768 + 16384 + wid*1024; \
    long ko_=(long)(Th)*128; \
    async16(src30+ko_, d_); async16(src31+ko_, d_+8192); }

#define LDA(MH, B_) { const char* p_ = smem + (B_)*32768 + (MH)*16384; \
    _Pragma("unroll") for (int m_=0;m_<4;++m_) \
    _Pragma("unroll") for (int k_=0;k_<2;++k_) \
        af[m_][k_] = *(const bf16x8*)(p_ + aoff[m_][k_]); }

#define LDB0(B_) { const char* p_ = smem + 65536 + (B_)*32768; \
    _Pragma("unroll") for (int n_=0;n_<2;++n_) \
    _Pragma("unroll") for (int k_=0;k_<2;++k_) \
        bfr0[n_][k_] = *(const bf16x8*)(p_ + boff[n_][k_]); }

#define LDB1(B_) { const char* p_ = smem + 65536 + (B_)*32768 + 16384; \
    _Pragma("unroll") for (int n_=0;n_<2;++n_) \
    _Pragma("unroll") for (int k_=0;k_<2;++k_) \
        bfr1[n_][k_] = *(const bf16x8*)(p_ + boff[n_][k_]); }

#define QMFMA(MH, NH, BSET) { \
    __builtin_amdgcn_s_setprio(1); \
    _Pragma("unroll") for (int m_=0;m_<4;++m_) \
    _Pragma("unroll") for (int n_=0;n_<2;++n_) \
    _Pragma("unroll") for (int k_=0;k_<2;++k_) \
        acc[(MH)*4+m_][(NH)*2+n_] = __builtin_amdgcn_mfma_f32_16x16x32_bf16( \
            af[m_][k_], bfr##BSET[n_][k_], acc[(MH)*4+m_][(NH)*2+n_], 0, 0, 0); \
    __builtin_amdgcn_s_setprio(0); }

#define MIDBAR { __builtin_amdgcn_s_barrier(); \
    asm volatile("s_waitcnt lgkmcnt(0)" ::: "memory"); }
#define ENDBAR(N) { asm volatile("s_waitcnt vmcnt(" #N ")" ::: "memory"); \
    __builtin_amdgcn_s_barrier(); }

__global__ __launch_bounds__(512, 2) void gemm256(
    const u16* __restrict__ A, const u16* __restrict__ B,
    float* __restrict__ C, int M, int N, int K) {
    extern __shared__ __align__(16) char smem[];

    const int tid = threadIdx.x;
    const int wid = tid >> 6;
    const int lane = tid & 63;
    const int fr = lane & 15;
    const int fkb = (lane >> 4) << 4;  // k-fragment byte offset
    const int wr = wid >> 2;           // 0..1  (M half)
    const int wc = wid & 3;            // 0..3  (N quarter)

    // XCD-aware bijective swizzle (nwg % 8 == 0 here)
    int nwg = gridDim.x, bid = blockIdx.x, swz = bid;
    if ((nwg & 7) == 0) swz = (bid & 7) * (nwg >> 3) + (bid >> 3);
    const int nbn = N >> 8;
    const long brow = (long)(swz / nbn) << 8;
    const long bcol = (long)(swz % nbn) << 8;
    const long rowb = (long)K * 2;

    // ---- stage source pointers (inverse-swizzled per-lane global addresses)
    const char *src00, *src01, *src10, *src11, *src20, *src21, *src30, *src31;
    {
#pragma unroll
        for (int c = 0; c < 2; ++c) {
            int p = wid * 1024 + c * 8192 + lane * 16;  // linear LDS dest off
            int l = SWZ(p);                              // logical element off
            int r2 = l >> 7, colb = l & 127;
            long gA = (long)((r2 & 63) + ((r2 >> 6) << 7));  // A sec0 row
            long gB = (long)((r2 & 31) + ((r2 >> 5) << 6));  // B sec0 row
            const char* a0 = (const char*)A + (brow + gA) * rowb + colb;
            const char* a1 = (const char*)A + (brow + gA + 64) * rowb + colb;
            const char* b0 = (const char*)B + (bcol + gB) * rowb + colb;
            const char* b1 = (const char*)B + (bcol + gB + 32) * rowb + colb;
            if (c == 0) { src00 = a0; src30 = a1; src10 = b0; src20 = b1; }
            else        { src01 = a0; src31 = a1; src11 = b0; src21 = b1; }
        }
    }

    // ---- swizzled LDS read offsets (within 16KiB section)
    int aoff[4][2], boff[2][2];
#pragma unroll
    for (int m = 0; m < 4; ++m)
#pragma unroll
        for (int ks = 0; ks < 2; ++ks) {
            int l = (((wr << 6) | (m << 4) | fr) << 7) | (ks << 6) | fkb;
            aoff[m][ks] = SWZ(l);
        }
#pragma unroll
    for (int n = 0; n < 2; ++n)
#pragma unroll
        for (int ks = 0; ks < 2; ++ks) {
            int l = (((wc << 5) | (n << 4) | fr) << 7) | (ks << 6) | fkb;
            boff[n][ks] = SWZ(l);
        }

    f32x4 acc[8][4];
#pragma unroll
    for (int i = 0; i < 8; ++i)
#pragma unroll
        for (int j = 0; j < 4; ++j) acc[i][j] = (f32x4){0.f, 0.f, 0.f, 0.f};

    bf16x8 af[4][2];    // A frags (current mhalf)
    bf16x8 bfr0[2][2];  // B set0 (nhalf=0)
    bf16x8 bfr1[2][2];  // B set1 (nhalf=1)

    // ---- prologue: stage halves 0..4, land h0,h1
    STAGE0(0); STAGE1(0); STAGE2(0); STAGE3(0); STAGE0(1);
    asm volatile("s_waitcnt vmcnt(6)" ::: "memory");
    __builtin_amdgcn_s_barrier();

    const int NT = K >> 6;
    for (int T = 0; T < NT - 2; ++T) {
        const int b = T & 1;
        LDA(0, b); LDB0(b);
        STAGE1(T + 1);
        MIDBAR; QMFMA(0, 0, 0); ENDBAR(6);

        LDB1(b);
        STAGE2(T + 1);
        MIDBAR; QMFMA(0, 1, 1); ENDBAR(6);

        LDA(1, b);
        STAGE3(T + 1);
        MIDBAR; QMFMA(1, 1, 1); ENDBAR(6);

        STAGE0(T + 2);
        MIDBAR; QMFMA(1, 0, 0); ENDBAR(6);
    }
    {   // tile NT-2: stage last 3 halves, start drain (vmcnt 4)
        const int T = NT - 2, b = T & 1;
        LDA(0, b); LDB0(b);
        STAGE1(T + 1);
        MIDBAR; QMFMA(0, 0, 0); ENDBAR(6);
        LDB1(b);
        STAGE2(T + 1);
        MIDBAR; QMFMA(0, 1, 1); ENDBAR(6);
        LDA(1, b);
        STAGE3(T + 1);
        MIDBAR; QMFMA(1, 1, 1); ENDBAR(6);
        MIDBAR; QMFMA(1, 0, 0); ENDBAR(4);
    }
    {   // tile NT-1: drain 2 -> 0
        const int T = NT - 1, b = T & 1;
        LDA(0, b); LDB0(b);
        MIDBAR; QMFMA(0, 0, 0); ENDBAR(2);
        LDB1(b);
        MIDBAR; QMFMA(0, 1, 1); ENDBAR(0);
        LDA(1, b);
        MIDBAR; QMFMA(1, 1, 1); __builtin_amdgcn_s_barrier();
        MIDBAR; QMFMA(1, 0, 0);
    }

    // ---- epilogue: C/D layout col = lane&15, row = (lane>>4)*4 + reg
    const long crow0 = brow + wr * 128 + ((lane >> 4) << 2);
    const long ccol0 = bcol + wc * 64 + fr;
#pragma unroll
    for (int mh = 0; mh < 2; ++mh)
#pragma unroll
        for (int m = 0; m < 4; ++m)
#pragma unroll
            for (int nh = 0; nh < 2; ++nh)
#pragma unroll
                for (int n = 0; n < 2; ++n)
#pragma unroll
                    for (int j = 0; j < 4; ++j) {
                        long r = crow0 + mh * 64 + m * 16 + j;
                        long cc = ccol0 + nh * 32 + n * 16;
                        C[r * (long)N + cc] = acc[mh * 4 + m][nh * 2 + n][j];
                    }
}

// ---------------------------------------------------------------------------
extern "C" void kernel_launch(void* const* d_in, const int* in_sizes, int n_in,
                              void* d_out, int out_size, void* d_ws, size_t ws_size,
                              hipStream_t stream) {
    const float* x = (const float*)d_in[0];   // [B,T,D] fp32, M = B*T
    const float* w = (const float*)d_in[1];   // [O,D] fp32
    float* out = (float*)d_out;               // [M,O] fp32

    const int K = 4096;
    const long M = (long)in_sizes[0] / K;     // 8192
    const long N = (long)in_sizes[1] / K;     // 4096

    u16* Adq = (u16*)d_ws;                    // [M,K] bf16 dequantized x
    u16* Bdq = Adq + (size_t)M * K;           // [N,K] bf16 dequantized w

    const long nblkA = M * (K / 128);
    const long nblkB = N * (K / 128);
    qdq_kernel<<<dim3((unsigned)((nblkA + 3) / 4)), dim3(256), 0, stream>>>(x, Adq, nblkA);
    qdq_kernel<<<dim3((unsigned)((nblkB + 3) / 4)), dim3(256), 0, stream>>>(w, Bdq, nblkB);

    static int smem_set = 0;
    if (!smem_set) {
        hipFuncSetAttribute((const void*)gemm256,
                            hipFuncAttributeMaxDynamicSharedMemorySize, 131072);
        smem_set = 1;
    }
    dim3 grid((unsigned)((M / 256) * (N / 256)));
    gemm256<<<grid, dim3(512), 131072, stream>>>(Adq, Bdq, out, (int)M, (int)N, K);
}

// Round 3
// 316.674 us; speedup vs baseline: 1.2537x; 1.0414x over previous
//
#include <hip/hip_runtime.h>

using u16 = unsigned short;
typedef __bf16 bf16x8 __attribute__((ext_vector_type(8)));
typedef float f32x4 __attribute__((ext_vector_type(4)));
typedef float f32x2 __attribute__((ext_vector_type(2)));

// ---------------------------------------------------------------------------
__device__ inline u16 f32_to_bf16_rne(float f) {
    unsigned u = __float_as_uint(f);
    u += 0x7FFFu + ((u >> 16) & 1u);
    return (u16)(u >> 16);
}

__device__ inline void async16(const void* g, void* l) {
    __builtin_amdgcn_global_load_lds(
        (__attribute__((address_space(1))) void*)(g),
        (__attribute__((address_space(3))) void*)(l),
        16, 0, 0);
}

// ---------------------------------------------------------------------------
// Quantize (per-128-block, scale = amax/448, fp8 e4m3fn RNE) then dequantize
// to bf16. One 64-lane wave per 128-element block. (HBM roofline: ~6.1 TB/s.)
__global__ void qdq_kernel(const float* __restrict__ in, u16* __restrict__ out,
                           long nblk) {
    long wid = (long)blockIdx.x * 4 + (threadIdx.x >> 6);
    int lane = threadIdx.x & 63;
    if (wid >= nblk) return;

    float2 v = reinterpret_cast<const float2*>(in + wid * 128)[lane];
    float a = fmaxf(fabsf(v.x), fabsf(v.y));
#pragma unroll
    for (int off = 32; off; off >>= 1) a = fmaxf(a, __shfl_xor(a, off));

    float s = a / 448.0f;
    float qx = v.x / s;
    float qy = v.y / s;
    qx = fminf(fmaxf(qx, -448.0f), 448.0f);
    qy = fminf(fmaxf(qy, -448.0f), 448.0f);

    int pk = __builtin_amdgcn_cvt_pk_fp8_f32(qx, qy, 0, false);
    f32x2 d = __builtin_amdgcn_cvt_pk_f32_fp8(pk, false);

    ushort2 o;
    o.x = f32_to_bf16_rne(d.x * s);
    o.y = f32_to_bf16_rne(d.y * s);
    reinterpret_cast<ushort2*>(out + wid * 128)[lane] = o;
}

// ---------------------------------------------------------------------------
// bf16 GEMM C[M,N] = A[M,K]*B[N,K]^T, fp32 acc. 256x256 8-phase template:
// BK=64, 8 waves (2x4), 128KiB LDS dbuf, counted vmcnt, setprio.
// LDS bank swizzle: byte ^= (row&7)<<4 (row = byte>>7; involution on bits
// 4-6). 16 lanes reading 16 consecutive rows at one 16B column now cover
// all 32 banks (rows 0-7) with free 2-way aliasing (rows 8-15). Applied
// BOTH sides: inverse-swizzled per-lane global staging source + swizzled
// ds_read offsets (rule #21).
// Halves per K-tile (consumption order):
//   j0: A-sec0   j1: B-sec0   j2: B-sec1   j3: A-sec1
// Phases per tile (quadrant Gray order): MFMA(0,0) (0,1) (1,1) (1,0);
// vmcnt(6) at end of every phase => all but newest 3 halves landed.

#define SWZ(x) ((x) ^ ((((x) >> 7) & 7) << 4))

#define STAGE0(Th) { int b_=(Th)&1; char* d_=smem + b_*32768 + wid*1024; \
    long ko_=(long)(Th)*128; \
    async16(src00+ko_, d_); async16(src01+ko_, d_+8192); }
#define STAGE1(Th) { int b_=(Th)&1; char* d_=smem + 65536 + b_*32768 + wid*1024; \
    long ko_=(long)(Th)*128; \
    async16(src10+ko_, d_); async16(src11+ko_, d_+8192); }
#define STAGE2(Th) { int b_=(Th)&1; char* d_=smem + 65536 + b_*32768 + 16384 + wid*1024; \
    long ko_=(long)(Th)*128; \
    async16(src20+ko_, d_); async16(src21+ko_, d_+8192); }
#define STAGE3(Th) { int b_=(Th)&1; char* d_=smem + b_*32768 + 16384 + wid*1024; \
    long ko_=(long)(Th)*128; \
    async16(src30+ko_, d_); async16(src31+ko_, d_+8192); }

#define LDA(MH, B_) { const char* p_ = smem + (B_)*32768 + (MH)*16384; \
    _Pragma("unroll") for (int m_=0;m_<4;++m_) \
    _Pragma("unroll") for (int k_=0;k_<2;++k_) \
        af[m_][k_] = *(const bf16x8*)(p_ + aoff[m_][k_]); }

#define LDB0(B_) { const char* p_ = smem + 65536 + (B_)*32768; \
    _Pragma("unroll") for (int n_=0;n_<2;++n_) \
    _Pragma("unroll") for (int k_=0;k_<2;++k_) \
        bfr0[n_][k_] = *(const bf16x8*)(p_ + boff[n_][k_]); }

#define LDB1(B_) { const char* p_ = smem + 65536 + (B_)*32768 + 16384; \
    _Pragma("unroll") for (int n_=0;n_<2;++n_) \
    _Pragma("unroll") for (int k_=0;k_<2;++k_) \
        bfr1[n_][k_] = *(const bf16x8*)(p_ + boff[n_][k_]); }

#define QMFMA(MH, NH, BSET) { \
    __builtin_amdgcn_s_setprio(1); \
    _Pragma("unroll") for (int m_=0;m_<4;++m_) \
    _Pragma("unroll") for (int n_=0;n_<2;++n_) \
    _Pragma("unroll") for (int k_=0;k_<2;++k_) \
        acc[(MH)*4+m_][(NH)*2+n_] = __builtin_amdgcn_mfma_f32_16x16x32_bf16( \
            af[m_][k_], bfr##BSET[n_][k_], acc[(MH)*4+m_][(NH)*2+n_], 0, 0, 0); \
    __builtin_amdgcn_s_setprio(0); }

#define MIDBAR { __builtin_amdgcn_s_barrier(); \
    asm volatile("s_waitcnt lgkmcnt(0)" ::: "memory"); }
#define ENDBAR(N) { asm volatile("s_waitcnt vmcnt(" #N ")" ::: "memory"); \
    __builtin_amdgcn_s_barrier(); }

__global__ __launch_bounds__(512, 2) void gemm256(
    const u16* __restrict__ A, const u16* __restrict__ B,
    float* __restrict__ C, int M, int N, int K) {
    extern __shared__ __align__(16) char smem[];

    const int tid = threadIdx.x;
    const int wid = tid >> 6;
    const int lane = tid & 63;
    const int fr = lane & 15;
    const int fkb = (lane >> 4) << 4;  // k-fragment byte offset
    const int wr = wid >> 2;           // 0..1  (M half)
    const int wc = wid & 3;            // 0..3  (N quarter)

    // XCD-aware bijective swizzle (nwg % 8 == 0 here)
    int nwg = gridDim.x, bid = blockIdx.x, swz = bid;
    if ((nwg & 7) == 0) swz = (bid & 7) * (nwg >> 3) + (bid >> 3);
    const int nbn = N >> 8;
    const long brow = (long)(swz / nbn) << 8;
    const long bcol = (long)(swz % nbn) << 8;
    const long rowb = (long)K * 2;

    // ---- stage source pointers (inverse-swizzled per-lane global addresses)
    const char *src00, *src01, *src10, *src11, *src20, *src21, *src30, *src31;
    {
#pragma unroll
        for (int c = 0; c < 2; ++c) {
            int p = wid * 1024 + c * 8192 + lane * 16;  // linear LDS dest off
            int l = SWZ(p);                              // logical byte off
            int r2 = l >> 7, colb = l & 127;
            long gA = (long)((r2 & 63) + ((r2 >> 6) << 7));  // A sec0 row
            long gB = (long)((r2 & 31) + ((r2 >> 5) << 6));  // B sec0 row
            const char* a0 = (const char*)A + (brow + gA) * rowb + colb;
            const char* a1 = (const char*)A + (brow + gA + 64) * rowb + colb;
            const char* b0 = (const char*)B + (bcol + gB) * rowb + colb;
            const char* b1 = (const char*)B + (bcol + gB + 32) * rowb + colb;
            if (c == 0) { src00 = a0; src30 = a1; src10 = b0; src20 = b1; }
            else        { src01 = a0; src31 = a1; src11 = b0; src21 = b1; }
        }
    }

    // ---- swizzled LDS read offsets (within 16KiB section)
    int aoff[4][2], boff[2][2];
#pragma unroll
    for (int m = 0; m < 4; ++m)
#pragma unroll
        for (int ks = 0; ks < 2; ++ks) {
            int l = (((wr << 6) | (m << 4) | fr) << 7) | (ks << 6) | fkb;
            aoff[m][ks] = SWZ(l);
        }
#pragma unroll
    for (int n = 0; n < 2; ++n)
#pragma unroll
        for (int ks = 0; ks < 2; ++ks) {
            int l = (((wc << 5) | (n << 4) | fr) << 7) | (ks << 6) | fkb;
            boff[n][ks] = SWZ(l);
        }

    f32x4 acc[8][4];
#pragma unroll
    for (int i = 0; i < 8; ++i)
#pragma unroll
        for (int j = 0; j < 4; ++j) acc[i][j] = (f32x4){0.f, 0.f, 0.f, 0.f};

    bf16x8 af[4][2];    // A frags (current mhalf)
    bf16x8 bfr0[2][2];  // B set0 (nhalf=0)
    bf16x8 bfr1[2][2];  // B set1 (nhalf=1)

    // ---- prologue: stage halves 0..4, land h0,h1
    STAGE0(0); STAGE1(0); STAGE2(0); STAGE3(0); STAGE0(1);
    asm volatile("s_waitcnt vmcnt(6)" ::: "memory");
    __builtin_amdgcn_s_barrier();

    const int NT = K >> 6;
    for (int T = 0; T < NT - 2; ++T) {
        const int b = T & 1;
        LDA(0, b); LDB0(b);
        STAGE1(T + 1);
        MIDBAR; QMFMA(0, 0, 0); ENDBAR(6);

        LDB1(b);
        STAGE2(T + 1);
        MIDBAR; QMFMA(0, 1, 1); ENDBAR(6);

        LDA(1, b);
        STAGE3(T + 1);
        MIDBAR; QMFMA(1, 1, 1); ENDBAR(6);

        STAGE0(T + 2);
        MIDBAR; QMFMA(1, 0, 0); ENDBAR(6);
    }
    {   // tile NT-2: stage last 3 halves, start drain (vmcnt 4)
        const int T = NT - 2, b = T & 1;
        LDA(0, b); LDB0(b);
        STAGE1(T + 1);
        MIDBAR; QMFMA(0, 0, 0); ENDBAR(6);
        LDB1(b);
        STAGE2(T + 1);
        MIDBAR; QMFMA(0, 1, 1); ENDBAR(6);
        LDA(1, b);
        STAGE3(T + 1);
        MIDBAR; QMFMA(1, 1, 1); ENDBAR(6);
        MIDBAR; QMFMA(1, 0, 0); ENDBAR(4);
    }
    {   // tile NT-1: drain 2 -> 0
        const int T = NT - 1, b = T & 1;
        LDA(0, b); LDB0(b);
        MIDBAR; QMFMA(0, 0, 0); ENDBAR(2);
        LDB1(b);
        MIDBAR; QMFMA(0, 1, 1); ENDBAR(0);
        LDA(1, b);
        MIDBAR; QMFMA(1, 1, 1); __builtin_amdgcn_s_barrier();
        MIDBAR; QMFMA(1, 0, 0);
    }

    // ---- epilogue: C/D layout col = lane&15, row = (lane>>4)*4 + reg
    const long crow0 = brow + wr * 128 + ((lane >> 4) << 2);
    const long ccol0 = bcol + wc * 64 + fr;
#pragma unroll
    for (int mh = 0; mh < 2; ++mh)
#pragma unroll
        for (int m = 0; m < 4; ++m)
#pragma unroll
            for (int nh = 0; nh < 2; ++nh)
#pragma unroll
                for (int n = 0; n < 2; ++n)
#pragma unroll
                    for (int j = 0; j < 4; ++j) {
                        long r = crow0 + mh * 64 + m * 16 + j;
                        long cc = ccol0 + nh * 32 + n * 16;
                        C[r * (long)N + cc] = acc[mh * 4 + m][nh * 2 + n][j];
                    }
}

// ---------------------------------------------------------------------------
extern "C" void kernel_launch(void* const* d_in, const int* in_sizes, int n_in,
                              void* d_out, int out_size, void* d_ws, size_t ws_size,
                              hipStream_t stream) {
    const float* x = (const float*)d_in[0];   // [B,T,D] fp32, M = B*T
    const float* w = (const float*)d_in[1];   // [O,D] fp32
    float* out = (float*)d_out;               // [M,O] fp32

    const int K = 4096;
    const long M = (long)in_sizes[0] / K;     // 8192
    const long N = (long)in_sizes[1] / K;     // 4096

    u16* Adq = (u16*)d_ws;                    // [M,K] bf16 dequantized x
    u16* Bdq = Adq + (size_t)M * K;           // [N,K] bf16 dequantized w

    const long nblkA = M * (K / 128);
    const long nblkB = N * (K / 128);
    qdq_kernel<<<dim3((unsigned)((nblkA + 3) / 4)), dim3(256), 0, stream>>>(x, Adq, nblkA);
    qdq_kernel<<<dim3((unsigned)((nblkB + 3) / 4)), dim3(256), 0, stream>>>(w, Bdq, nblkB);

    static int smem_set = 0;
    if (!smem_set) {
        hipFuncSetAttribute((const void*)gemm256,
                            hipFuncAttributeMaxDynamicSharedMemorySize, 131072);
        smem_set = 1;
    }
    dim3 grid((unsigned)((M / 256) * (N / 256)));
    gemm256<<<grid, dim3(512), 131072, stream>>>(Adq, Bdq, out, (int)M, (int)N, K);
}

// Round 4
// 314.734 us; speedup vs baseline: 1.2614x; 1.0062x over previous
//
#include <hip/hip_runtime.h>

using u16 = unsigned short;
typedef __bf16 bf16x8 __attribute__((ext_vector_type(8)));
typedef float f32x4 __attribute__((ext_vector_type(4)));
typedef float f32x2 __attribute__((ext_vector_type(2)));

// ---------------------------------------------------------------------------
__device__ inline u16 f32_to_bf16_rne(float f) {
    unsigned u = __float_as_uint(f);
    u += 0x7FFFu + ((u >> 16) & 1u);
    return (u16)(u >> 16);
}

__device__ inline void async16(const void* g, void* l) {
    __builtin_amdgcn_global_load_lds(
        (__attribute__((address_space(1))) void*)(g),
        (__attribute__((address_space(3))) void*)(l),
        16, 0, 0);
}

// ---------------------------------------------------------------------------
// Quantize (per-128-block, scale = amax/448, fp8 e4m3fn RNE) then dequantize
// to bf16. One 64-lane wave per 128-element block. (HBM roofline: ~6.1 TB/s.)
__global__ void qdq_kernel(const float* __restrict__ in, u16* __restrict__ out,
                           long nblk) {
    long wid = (long)blockIdx.x * 4 + (threadIdx.x >> 6);
    int lane = threadIdx.x & 63;
    if (wid >= nblk) return;

    float2 v = reinterpret_cast<const float2*>(in + wid * 128)[lane];
    float a = fmaxf(fabsf(v.x), fabsf(v.y));
#pragma unroll
    for (int off = 32; off; off >>= 1) a = fmaxf(a, __shfl_xor(a, off));

    float s = a / 448.0f;
    float qx = v.x / s;
    float qy = v.y / s;
    qx = fminf(fmaxf(qx, -448.0f), 448.0f);
    qy = fminf(fmaxf(qy, -448.0f), 448.0f);

    int pk = __builtin_amdgcn_cvt_pk_fp8_f32(qx, qy, 0, false);
    f32x2 d = __builtin_amdgcn_cvt_pk_f32_fp8(pk, false);

    ushort2 o;
    o.x = f32_to_bf16_rne(d.x * s);
    o.y = f32_to_bf16_rne(d.y * s);
    reinterpret_cast<ushort2*>(out + wid * 128)[lane] = o;
}

// ---------------------------------------------------------------------------
// bf16 GEMM C[M,N] = A[M,K]*B[N,K]^T, fp32 acc. 256x256 8-phase template:
// BK=64, 8 waves (2x4), 128KiB LDS dbuf, swizzle byte^=(row&7)<<4 both-sides,
// counted vmcnt ONCE per K-tile, setprio.
// Half index h = 4T+j, j: 0=A0 1=B0 2=B1 3=A1 (stage order == consume order).
// Stage schedule (7 halves ahead): tile T phase p stages half 4T+6+p:
//   p1 -> A1(T+1), p2 -> A0(T+2), p3 -> B0(T+2), p4 -> B1(T+2)
// Ledger: ENDBAR(6) at p4 leaves the 3 newest halves (= all of tile T+2's
// staged-so-far) unlanded; everything through A1(T+1) landed => tile T+1
// needs NO vmcnt inside. WAR: each slot's re-stage issues >=1 phase after
// its last read (reads drained by lgkmcnt(0) before the phase-end barrier).

#define SWZ(x) ((x) ^ ((((x) >> 7) & 7) << 4))

#define STAGE0(Th) { int b_=(Th)&1; char* d_=smem + b_*32768 + wid*1024; \
    long ko_=(long)(Th)*128; \
    async16(src00+ko_, d_); async16(src01+ko_, d_+8192); }
#define STAGE1(Th) { int b_=(Th)&1; char* d_=smem + 65536 + b_*32768 + wid*1024; \
    long ko_=(long)(Th)*128; \
    async16(src10+ko_, d_); async16(src11+ko_, d_+8192); }
#define STAGE2(Th) { int b_=(Th)&1; char* d_=smem + 65536 + b_*32768 + 16384 + wid*1024; \
    long ko_=(long)(Th)*128; \
    async16(src20+ko_, d_); async16(src21+ko_, d_+8192); }
#define STAGE3(Th) { int b_=(Th)&1; char* d_=smem + b_*32768 + 16384 + wid*1024; \
    long ko_=(long)(Th)*128; \
    async16(src30+ko_, d_); async16(src31+ko_, d_+8192); }

#define LDA(MH, B_) { const char* p_ = smem + (B_)*32768 + (MH)*16384; \
    _Pragma("unroll") for (int m_=0;m_<4;++m_) \
    _Pragma("unroll") for (int k_=0;k_<2;++k_) \
        af[m_][k_] = *(const bf16x8*)(p_ + aoff[m_][k_]); }

#define LDB0(B_) { const char* p_ = smem + 65536 + (B_)*32768; \
    _Pragma("unroll") for (int n_=0;n_<2;++n_) \
    _Pragma("unroll") for (int k_=0;k_<2;++k_) \
        bfr0[n_][k_] = *(const bf16x8*)(p_ + boff[n_][k_]); }

#define LDB1(B_) { const char* p_ = smem + 65536 + (B_)*32768 + 16384; \
    _Pragma("unroll") for (int n_=0;n_<2;++n_) \
    _Pragma("unroll") for (int k_=0;k_<2;++k_) \
        bfr1[n_][k_] = *(const bf16x8*)(p_ + boff[n_][k_]); }

#define QMFMA(MH, NH, BSET) { \
    __builtin_amdgcn_s_setprio(1); \
    _Pragma("unroll") for (int m_=0;m_<4;++m_) \
    _Pragma("unroll") for (int n_=0;n_<2;++n_) \
    _Pragma("unroll") for (int k_=0;k_<2;++k_) \
        acc[(MH)*4+m_][(NH)*2+n_] = __builtin_amdgcn_mfma_f32_16x16x32_bf16( \
            af[m_][k_], bfr##BSET[n_][k_], acc[(MH)*4+m_][(NH)*2+n_], 0, 0, 0); \
    __builtin_amdgcn_s_setprio(0); }

#define MIDBAR { __builtin_amdgcn_s_barrier(); \
    asm volatile("s_waitcnt lgkmcnt(0)" ::: "memory"); }
#define BAR { __builtin_amdgcn_s_barrier(); }
#define ENDBAR(N) { asm volatile("s_waitcnt vmcnt(" #N ")" ::: "memory"); \
    __builtin_amdgcn_s_barrier(); }

__global__ __launch_bounds__(512, 2) void gemm256(
    const u16* __restrict__ A, const u16* __restrict__ B,
    float* __restrict__ C, int M, int N, int K) {
    extern __shared__ __align__(16) char smem[];

    const int tid = threadIdx.x;
    const int wid = tid >> 6;
    const int lane = tid & 63;
    const int fr = lane & 15;
    const int fkb = (lane >> 4) << 4;  // k-fragment byte offset
    const int wr = wid >> 2;           // 0..1  (M half)
    const int wc = wid & 3;            // 0..3  (N quarter)

    // XCD-aware bijective swizzle (nwg % 8 == 0 here)
    int nwg = gridDim.x, bid = blockIdx.x, swz = bid;
    if ((nwg & 7) == 0) swz = (bid & 7) * (nwg >> 3) + (bid >> 3);
    const int nbn = N >> 8;
    const long brow = (long)(swz / nbn) << 8;
    const long bcol = (long)(swz % nbn) << 8;
    const long rowb = (long)K * 2;

    // ---- stage source pointers (inverse-swizzled per-lane global addresses)
    const char *src00, *src01, *src10, *src11, *src20, *src21, *src30, *src31;
    {
#pragma unroll
        for (int c = 0; c < 2; ++c) {
            int p = wid * 1024 + c * 8192 + lane * 16;  // linear LDS dest off
            int l = SWZ(p);                              // logical byte off
            int r2 = l >> 7, colb = l & 127;
            long gA = (long)((r2 & 63) + ((r2 >> 6) << 7));  // A sec0 row
            long gB = (long)((r2 & 31) + ((r2 >> 5) << 6));  // B sec0 row
            const char* a0 = (const char*)A + (brow + gA) * rowb + colb;
            const char* a1 = (const char*)A + (brow + gA + 64) * rowb + colb;
            const char* b0 = (const char*)B + (bcol + gB) * rowb + colb;
            const char* b1 = (const char*)B + (bcol + gB + 32) * rowb + colb;
            if (c == 0) { src00 = a0; src30 = a1; src10 = b0; src20 = b1; }
            else        { src01 = a0; src31 = a1; src11 = b0; src21 = b1; }
        }
    }

    // ---- swizzled LDS read offsets (within 16KiB section)
    int aoff[4][2], boff[2][2];
#pragma unroll
    for (int m = 0; m < 4; ++m)
#pragma unroll
        for (int ks = 0; ks < 2; ++ks) {
            int l = (((wr << 6) | (m << 4) | fr) << 7) | (ks << 6) | fkb;
            aoff[m][ks] = SWZ(l);
        }
#pragma unroll
    for (int n = 0; n < 2; ++n)
#pragma unroll
        for (int ks = 0; ks < 2; ++ks) {
            int l = (((wc << 5) | (n << 4) | fr) << 7) | (ks << 6) | fkb;
            boff[n][ks] = SWZ(l);
        }

    f32x4 acc[8][4];
#pragma unroll
    for (int i = 0; i < 8; ++i)
#pragma unroll
        for (int j = 0; j < 4; ++j) acc[i][j] = (f32x4){0.f, 0.f, 0.f, 0.f};

    bf16x8 af[4][2];    // A frags (current mhalf)
    bf16x8 bfr0[2][2];  // B set0 (nhalf=0)
    bf16x8 bfr1[2][2];  // B set1 (nhalf=1)

    // ---- prologue: stage halves h0..h6 (tile0 + 3/4 of tile1), land tile0
    STAGE0(0); STAGE1(0); STAGE2(0); STAGE3(0);
    STAGE0(1); STAGE1(1); STAGE2(1);
    asm volatile("s_waitcnt vmcnt(6)" ::: "memory");
    __builtin_amdgcn_s_barrier();

    const int NT = K >> 6;
    for (int T = 0; T < NT - 2; ++T) {
        const int b = T & 1;
        LDA(0, b); LDB0(b);
        STAGE3(T + 1);
        MIDBAR; QMFMA(0, 0, 0); BAR;

        LDB1(b);
        STAGE0(T + 2);
        MIDBAR; QMFMA(0, 1, 1); BAR;

        LDA(1, b);
        STAGE1(T + 2);
        MIDBAR; QMFMA(1, 1, 1); BAR;

        STAGE2(T + 2);
        MIDBAR; QMFMA(1, 0, 0); ENDBAR(6);
    }
    {   // tile NT-2: stage only the final half A1(NT-1), then full drain
        const int T = NT - 2, b = T & 1;
        LDA(0, b); LDB0(b);
        STAGE3(T + 1);
        MIDBAR; QMFMA(0, 0, 0); BAR;
        LDB1(b);
        MIDBAR; QMFMA(0, 1, 1); BAR;
        LDA(1, b);
        MIDBAR; QMFMA(1, 1, 1); BAR;
        MIDBAR; QMFMA(1, 0, 0); ENDBAR(0);
    }
    {   // tile NT-1: no stages
        const int b = (NT - 1) & 1;
        LDA(0, b); LDB0(b);
        MIDBAR; QMFMA(0, 0, 0); BAR;
        LDB1(b);
        MIDBAR; QMFMA(0, 1, 1); BAR;
        LDA(1, b);
        MIDBAR; QMFMA(1, 1, 1); BAR;
        MIDBAR; QMFMA(1, 0, 0);
    }

    // ---- epilogue: C/D layout col = lane&15, row = (lane>>4)*4 + reg
    const long crow0 = brow + wr * 128 + ((lane >> 4) << 2);
    const long ccol0 = bcol + wc * 64 + fr;
#pragma unroll
    for (int mh = 0; mh < 2; ++mh)
#pragma unroll
        for (int m = 0; m < 4; ++m)
#pragma unroll
            for (int nh = 0; nh < 2; ++nh)
#pragma unroll
                for (int n = 0; n < 2; ++n)
#pragma unroll
                    for (int j = 0; j < 4; ++j) {
                        long r = crow0 + mh * 64 + m * 16 + j;
                        long cc = ccol0 + nh * 32 + n * 16;
                        C[r * (long)N + cc] = acc[mh * 4 + m][nh * 2 + n][j];
                    }
}

// ---------------------------------------------------------------------------
extern "C" void kernel_launch(void* const* d_in, const int* in_sizes, int n_in,
                              void* d_out, int out_size, void* d_ws, size_t ws_size,
                              hipStream_t stream) {
    const float* x = (const float*)d_in[0];   // [B,T,D] fp32, M = B*T
    const float* w = (const float*)d_in[1];   // [O,D] fp32
    float* out = (float*)d_out;               // [M,O] fp32

    const int K = 4096;
    const long M = (long)in_sizes[0] / K;     // 8192
    const long N = (long)in_sizes[1] / K;     // 4096

    u16* Adq = (u16*)d_ws;                    // [M,K] bf16 dequantized x
    u16* Bdq = Adq + (size_t)M * K;           // [N,K] bf16 dequantized w

    const long nblkA = M * (K / 128);
    const long nblkB = N * (K / 128);
    qdq_kernel<<<dim3((unsigned)((nblkA + 3) / 4)), dim3(256), 0, stream>>>(x, Adq, nblkA);
    qdq_kernel<<<dim3((unsigned)((nblkB + 3) / 4)), dim3(256), 0, stream>>>(w, Bdq, nblkB);

    static int smem_set = 0;
    if (!smem_set) {
        hipFuncSetAttribute((const void*)gemm256,
                            hipFuncAttributeMaxDynamicSharedMemorySize, 131072);
        smem_set = 1;
    }
    dim3 grid((unsigned)((M / 256) * (N / 256)));
    gemm256<<<grid, dim3(512), 131072, stream>>>(Adq, Bdq, out, (int)M, (int)N, K);
}

// Round 5
// 305.811 us; speedup vs baseline: 1.2982x; 1.0292x over previous
//
#include <hip/hip_runtime.h>

using u16 = unsigned short;
typedef __bf16 bf16x8 __attribute__((ext_vector_type(8)));
typedef float f32x4 __attribute__((ext_vector_type(4)));
typedef float f32x2 __attribute__((ext_vector_type(2)));

// ---------------------------------------------------------------------------
__device__ inline u16 f32_to_bf16_rne(float f) {
    unsigned u = __float_as_uint(f);
    u += 0x7FFFu + ((u >> 16) & 1u);
    return (u16)(u >> 16);
}

__device__ inline void async16(const void* g, void* l) {
    __builtin_amdgcn_global_load_lds(
        (__attribute__((address_space(1))) void*)(g),
        (__attribute__((address_space(3))) void*)(l),
        16, 0, 0);
}

// ---------------------------------------------------------------------------
__global__ void qdq_kernel(const float* __restrict__ in, u16* __restrict__ out,
                           long nblk) {
    long wid = (long)blockIdx.x * 4 + (threadIdx.x >> 6);
    int lane = threadIdx.x & 63;
    if (wid >= nblk) return;

    float2 v = reinterpret_cast<const float2*>(in + wid * 128)[lane];
    float a = fmaxf(fabsf(v.x), fabsf(v.y));
#pragma unroll
    for (int off = 32; off; off >>= 1) a = fmaxf(a, __shfl_xor(a, off));

    float s = a / 448.0f;
    float qx = v.x / s;
    float qy = v.y / s;
    qx = fminf(fmaxf(qx, -448.0f), 448.0f);
    qy = fminf(fmaxf(qy, -448.0f), 448.0f);

    int pk = __builtin_amdgcn_cvt_pk_fp8_f32(qx, qy, 0, false);
    f32x2 d = __builtin_amdgcn_cvt_pk_f32_fp8(pk, false);

    ushort2 o;
    o.x = f32_to_bf16_rne(d.x * s);
    o.y = f32_to_bf16_rne(d.y * s);
    reinterpret_cast<ushort2*>(out + wid * 128)[lane] = o;
}

// ---------------------------------------------------------------------------
// bf16 GEMM C=A*B^T, fp32 acc. 256x256, BK=64, 8 waves (2x4), 128KiB LDS
// dbuf, swizzle byte^=(row&7)<<4 both-sides.
// PIPELINED phases: each phase's ds_reads are issued in the PREVIOUS phase
// (pre- or post-MFMA) so LDS service hides under MFMA. Quadrant order
// p1=(1,0) p2=(1,1) p3=(0,1) p4=(0,0). One barrier/phase.
// Read issues:  B1(T)@p1-pre, A0(T)@p2-post, B0(T+1)@p3-post, A1(T+1)@p4-post
// lgkm waits:   p1: cnt(4)   p2: cnt(0)     p3: cnt(0)        p4: none
// Stage order:  A0(T+1)@p1, A1(T+2)@p2, B0(T+2)@p3, B1(T+2)@p4
// vmcnt @phase end: p1:8  p2:6  p3:10  p4:8  (each exactly guarantees the
// next phase's read-issue target is landed; verified ledger, 2 loads/stage).
// b0 frags double-buffered (b0e/b0o per tile parity); af/b1 single sets.

#define SWZ(x) ((x) ^ ((((x) >> 7) & 7) << 4))

#define STAGE_A0(Th) { int b_=(Th)&1; char* d_=smem + b_*32768 + wid*1024; \
    long ko_=(long)(Th)*128; \
    async16(src00+ko_, d_); async16(src01+ko_, d_+8192); }
#define STAGE_B0(Th) { int b_=(Th)&1; char* d_=smem + 65536 + b_*32768 + wid*1024; \
    long ko_=(long)(Th)*128; \
    async16(src10+ko_, d_); async16(src11+ko_, d_+8192); }
#define STAGE_B1(Th) { int b_=(Th)&1; char* d_=smem + 65536 + b_*32768 + 16384 + wid*1024; \
    long ko_=(long)(Th)*128; \
    async16(src20+ko_, d_); async16(src21+ko_, d_+8192); }
#define STAGE_A1(Th) { int b_=(Th)&1; char* d_=smem + b_*32768 + 16384 + wid*1024; \
    long ko_=(long)(Th)*128; \
    async16(src30+ko_, d_); async16(src31+ko_, d_+8192); }

// ds_read issues: base pointers pA0/pA1 (per k-slot), pB0/pB1; compile-time
// immediates BUF*32768 + MH*16384 + m*2048 (A) / NH*16384 + n*2048 (B).
#define LD_AF(MH, BUF) { \
    _Pragma("unroll") for (int m_=0;m_<4;++m_) { \
        af[m_][0] = *(const bf16x8*)(pA0 + (BUF)*32768 + (MH)*16384 + m_*2048); \
        af[m_][1] = *(const bf16x8*)(pA1 + (BUF)*32768 + (MH)*16384 + m_*2048); } }
#define LD_B1(BUF) { \
    _Pragma("unroll") for (int n_=0;n_<2;++n_) { \
        b1[n_][0] = *(const bf16x8*)(pB0 + (BUF)*32768 + 16384 + n_*2048); \
        b1[n_][1] = *(const bf16x8*)(pB1 + (BUF)*32768 + 16384 + n_*2048); } }
#define LD_B0(BV, BUF) { \
    _Pragma("unroll") for (int n_=0;n_<2;++n_) { \
        BV[n_][0] = *(const bf16x8*)(pB0 + (BUF)*32768 + n_*2048); \
        BV[n_][1] = *(const bf16x8*)(pB1 + (BUF)*32768 + n_*2048); } }

#define MF(MH, NH, BV) { \
    __builtin_amdgcn_s_setprio(1); \
    _Pragma("unroll") for (int m_=0;m_<4;++m_) \
    _Pragma("unroll") for (int n_=0;n_<2;++n_) \
    _Pragma("unroll") for (int k_=0;k_<2;++k_) \
        acc[(MH)*4+m_][(NH)*2+n_] = __builtin_amdgcn_mfma_f32_16x16x32_bf16( \
            af[m_][k_], BV[n_][k_], acc[(MH)*4+m_][(NH)*2+n_], 0, 0, 0); \
    __builtin_amdgcn_s_setprio(0); }

#define SB __builtin_amdgcn_sched_barrier(0);
#define LGKM(n) { asm volatile("s_waitcnt lgkmcnt(" #n ")" ::: "memory"); SB }
#define VMC(n)  { asm volatile("s_waitcnt vmcnt(" #n ")" ::: "memory"); SB }
#define BARRIER { __builtin_amdgcn_s_barrier(); SB }

// One steady-state tile. BUF = T&1 (literal), B0CUR = b0 set for T,
// B0NXT = set for T+1.
#define TILE_STEADY(Tv, BUF, NBUF, B0CUR, B0NXT) { \
    /* P1 */ \
    LD_B1(BUF); \
    STAGE_A0((Tv)+1); \
    SB LGKM(4); \
    MF(1,0,B0CUR); SB \
    VMC(8); BARRIER; \
    /* P2 */ \
    LGKM(0); \
    MF(1,1,b1); SB \
    LD_AF(0, BUF); \
    STAGE_A1((Tv)+2); \
    SB VMC(6); BARRIER; \
    /* P3 */ \
    LGKM(0); \
    MF(0,1,b1); SB \
    LD_B0(B0NXT, NBUF); \
    STAGE_B0((Tv)+2); \
    SB VMC(10); BARRIER; \
    /* P4 */ \
    MF(0,0,B0CUR); SB \
    LD_AF(1, NBUF); \
    STAGE_B1((Tv)+2); \
    SB VMC(8); BARRIER; }

__global__ __launch_bounds__(512, 2) void gemm256(
    const u16* __restrict__ A, const u16* __restrict__ B,
    float* __restrict__ C, int M, int N, int K) {
    extern __shared__ __align__(16) char smem[];

    const int tid = threadIdx.x;
    const int wid = tid >> 6;
    const int lane = tid & 63;
    const int fr = lane & 15;
    const int wr = wid >> 2;
    const int wc = wid & 3;

    int nwg = gridDim.x, bid = blockIdx.x, swz = bid;
    if ((nwg & 7) == 0) swz = (bid & 7) * (nwg >> 3) + (bid >> 3);
    const int nbn = N >> 8;
    const long brow = (long)(swz / nbn) << 8;
    const long bcol = (long)(swz % nbn) << 8;
    const long rowb = (long)K * 2;

    // stage source pointers (inverse-swizzled per-lane global addresses)
    const char *src00, *src01, *src10, *src11, *src20, *src21, *src30, *src31;
    {
#pragma unroll
        for (int c = 0; c < 2; ++c) {
            int p = wid * 1024 + c * 8192 + lane * 16;
            int l = SWZ(p);
            int r2 = l >> 7, colb = l & 127;
            long gA = (long)((r2 & 63) + ((r2 >> 6) << 7));
            long gB = (long)((r2 & 31) + ((r2 >> 5) << 6));
            const char* a0 = (const char*)A + (brow + gA) * rowb + colb;
            const char* a1 = (const char*)A + (brow + gA + 64) * rowb + colb;
            const char* b0 = (const char*)B + (bcol + gB) * rowb + colb;
            const char* b1p = (const char*)B + (bcol + gB + 32) * rowb + colb;
            if (c == 0) { src00 = a0; src30 = a1; src10 = b0; src20 = b1p; }
            else        { src01 = a0; src31 = a1; src11 = b0; src21 = b1p; }
        }
    }

    // ds_read base pointers: phys = (row<<7)|(ks<<6)|fkb XOR (fr&7)<<4;
    // per-lane constant part: bit6 = ks^fr2, bits4-5 = (lane>>4)^(fr&3).
    const int fr2 = (fr >> 2) & 1;
    const int c45 = ((lane >> 4) ^ (fr & 3)) << 4;
    const char* pA0 = smem + (wr << 13) + (fr << 7) + ((0 ^ fr2) << 6) + c45;
    const char* pA1 = smem + (wr << 13) + (fr << 7) + ((1 ^ fr2) << 6) + c45;
    const char* pB0 = smem + 65536 + (wc << 12) + (fr << 7) + ((0 ^ fr2) << 6) + c45;
    const char* pB1 = smem + 65536 + (wc << 12) + (fr << 7) + ((1 ^ fr2) << 6) + c45;

    f32x4 acc[8][4];
#pragma unroll
    for (int i = 0; i < 8; ++i)
#pragma unroll
        for (int j = 0; j < 4; ++j) acc[i][j] = (f32x4){0.f, 0.f, 0.f, 0.f};

    bf16x8 af[4][2];   // A frags (A1 during p1-p2, A0 during p3-p4)
    bf16x8 b0e[2][2];  // B0 for even tiles
    bf16x8 b0o[2][2];  // B0 for odd tiles
    bf16x8 b1[2][2];   // B1 (single set)

    // ---- prologue: stage A0(0),A1(0),B0(0),B1(0),A1(1),B0(1),B1(1)
    STAGE_A0(0); STAGE_A1(0); STAGE_B0(0); STAGE_B1(0);
    STAGE_A1(1); STAGE_B0(1); STAGE_B1(1);
    VMC(8); BARRIER;          // lands A0(0),A1(0),B0(0)
    LD_B0(b0e, 0);            // B0(0) reads  ("p3(-1)-post")
    LD_AF(1, 0);              // A1(0) reads  ("p4(-1)-post")
    SB VMC(6); BARRIER;       // lands B1(0) for p1(0)'s read-issue

    const int NT = K >> 6;    // 64
    for (int T = 0; T + 3 < NT; T += 2) {
        TILE_STEADY(T,     0, 1, b0e, b0o);
        TILE_STEADY(T + 1, 1, 0, b0o, b0e);
    }
    {   // tile NT-2 (=62, buf0): stages only A0(63); tightened vmcnts
        LD_B1(0);
        STAGE_A0(NT - 1);
        SB LGKM(4);
        MF(1,0,b0e); SB
        VMC(8); BARRIER;

        LGKM(0);
        MF(1,1,b1); SB
        LD_AF(0, 0);
        SB VMC(4); BARRIER;

        LGKM(0);
        MF(0,1,b1); SB
        LD_B0(b0o, 1);
        SB BARRIER;

        MF(0,0,b0e); SB
        LD_AF(1, 1);
        SB VMC(2); BARRIER;
    }
    {   // tile NT-1 (=63, buf1): no stages
        LD_B1(1);
        SB LGKM(4);
        MF(1,0,b0o); SB
        VMC(0); BARRIER;

        LGKM(0);
        MF(1,1,b1); SB
        LD_AF(0, 1);
        SB BARRIER;

        LGKM(0);
        MF(0,1,b1); SB
        BARRIER;

        MF(0,0,b0o);
    }

    // ---- epilogue: C/D layout col = lane&15, row = (lane>>4)*4 + reg
    const long crow0 = brow + wr * 128 + ((lane >> 4) << 2);
    const long ccol0 = bcol + wc * 64 + fr;
#pragma unroll
    for (int mh = 0; mh < 2; ++mh)
#pragma unroll
        for (int m = 0; m < 4; ++m)
#pragma unroll
            for (int nh = 0; nh < 2; ++nh)
#pragma unroll
                for (int n = 0; n < 2; ++n)
#pragma unroll
                    for (int j = 0; j < 4; ++j) {
                        long r = crow0 + mh * 64 + m * 16 + j;
                        long cc = ccol0 + nh * 32 + n * 16;
                        C[r * (long)N + cc] = acc[mh * 4 + m][nh * 2 + n][j];
                    }
}

// ---------------------------------------------------------------------------
extern "C" void kernel_launch(void* const* d_in, const int* in_sizes, int n_in,
                              void* d_out, int out_size, void* d_ws, size_t ws_size,
                              hipStream_t stream) {
    const float* x = (const float*)d_in[0];
    const float* w = (const float*)d_in[1];
    float* out = (float*)d_out;

    const int K = 4096;
    const long M = (long)in_sizes[0] / K;     // 8192
    const long N = (long)in_sizes[1] / K;     // 4096

    u16* Adq = (u16*)d_ws;
    u16* Bdq = Adq + (size_t)M * K;

    const long nblkA = M * (K / 128);
    const long nblkB = N * (K / 128);
    qdq_kernel<<<dim3((unsigned)((nblkA + 3) / 4)), dim3(256), 0, stream>>>(x, Adq, nblkA);
    qdq_kernel<<<dim3((unsigned)((nblkB + 3) / 4)), dim3(256), 0, stream>>>(w, Bdq, nblkB);

    static int smem_set = 0;
    if (!smem_set) {
        hipFuncSetAttribute((const void*)gemm256,
                            hipFuncAttributeMaxDynamicSharedMemorySize, 131072);
        smem_set = 1;
    }
    dim3 grid((unsigned)((M / 256) * (N / 256)));
    gemm256<<<grid, dim3(512), 131072, stream>>>(Adq, Bdq, out, (int)M, (int)N, K);
}

// Round 6
// 289.744 us; speedup vs baseline: 1.3702x; 1.0555x over previous
//
#include <hip/hip_runtime.h>

using u16 = unsigned short;
typedef int i32x4 __attribute__((ext_vector_type(4)));
typedef int i32x8 __attribute__((ext_vector_type(8)));
typedef float f32x4 __attribute__((ext_vector_type(4)));
typedef float f32x2 __attribute__((ext_vector_type(2)));
typedef float f32x16 __attribute__((ext_vector_type(16)));

#define SC1 0x7F7F7F7F  // e8m0 scale bytes = 2^0 = 1.0

// ---------------------------------------------------------------------------
__device__ inline void async16(const void* g, void* l) {
    __builtin_amdgcn_global_load_lds(
        (__attribute__((address_space(1))) void*)(g),
        (__attribute__((address_space(3))) void*)(l),
        16, 0, 0);
}

__device__ inline i32x8 mk8(i32x4 lo, i32x4 hi) {
    return __builtin_shufflevector(lo, hi, 0, 1, 2, 3, 4, 5, 6, 7);
}

// ---------------------------------------------------------------------------
// Quantize per-128-block: scale = amax/448 (fp32), payload fp8 e4m3fn RNE.
// Outputs: fp8 payload [R][K] row-major; scales TRANSPOSED [K/128][R] so the
// GEMM can stage 256 consecutive row-scales per k-block with one load.
__global__ void quant_kernel(const float* __restrict__ in,
                             u16* __restrict__ outq,   // 2 fp8 per u16
                             float* __restrict__ outs, // [32][R]
                             long R) {
    long wid = (long)blockIdx.x * 4 + (threadIdx.x >> 6);
    int lane = threadIdx.x & 63;
    if (wid >= R * 32) return;

    float2 v = reinterpret_cast<const float2*>(in + wid * 128)[lane];
    float a = fmaxf(fabsf(v.x), fabsf(v.y));
#pragma unroll
    for (int off = 32; off; off >>= 1) a = fmaxf(a, __shfl_xor(a, off));

    float s = a / 448.0f;               // fp32 IEEE divide, matches jnp
    float qx = v.x / s;
    float qy = v.y / s;
    qx = fminf(fmaxf(qx, -448.0f), 448.0f);
    qy = fminf(fmaxf(qy, -448.0f), 448.0f);

    int pk = __builtin_amdgcn_cvt_pk_fp8_f32(qx, qy, 0, false); // RNE e4m3fn
    outq[wid * 64 + lane] = (u16)(pk & 0xFFFF);

    if (lane == 0) {
        long row = wid >> 5, kb = wid & 31;
        outs[kb * R + row] = s;
    }
}

// ---------------------------------------------------------------------------
// fp8 block-scaled GEMM: C[M,N] = sum_kb (Aq_kb @ Bq_kb^T) * sa[:,kb]*sb[:,kb]
// 256x256 tile, 8 waves (2x4, wave tile 128x64), slab = K-block of 128 fp8.
// mfma_scale_f32_32x32x64_f8f6f4 with HW scale = 1.0 (exact); fp32 rescale
// per 128-k-block via FMA (reference math, fp32 accumulate).
// LDS: A[2][32KB] @0, B[2][32KB] @64KB, Sa[2][1KB] @128KB, Sb[2][1KB] @130KB.
// Swizzle byte^=(row&7)<<4 both-sides (row = byte>>7; fp8 rows are 128B).
// Simple m97-style loop: stage kb+1, read+compute kb, vmcnt(0)+barrier.

#define SWZ(x) ((x) ^ ((((x) >> 7) & 7) << 4))

__global__ __launch_bounds__(512, 2) void gemm_fp8(
    const char* __restrict__ Aq, const char* __restrict__ Bq,
    const float* __restrict__ AscaleG, const float* __restrict__ BscaleG,
    float* __restrict__ C, int M, int N) {
    extern __shared__ __align__(16) char smem[];
    const int KB = 4096;  // bytes per fp8 row

    const int tid = threadIdx.x;
    const int wid = tid >> 6;
    const int lane = tid & 63;
    const int l31 = lane & 31;
    const int lh = lane >> 5;           // k-half lane group
    const int wr = wid >> 2;            // 0..1 (M half)
    const int wc = wid & 3;             // 0..3 (N quarter)

    // XCD-aware bijective swizzle (nwg % 8 == 0 here)
    int nwg = gridDim.x, bid = blockIdx.x, swz = bid;
    if ((nwg & 7) == 0) swz = (bid & 7) * (nwg >> 3) + (bid >> 3);
    const int nbn = N >> 8;
    const long brow = (long)(swz / nbn) << 8;
    const long bcol = (long)(swz % nbn) << 8;

    const char* Abase = Aq + brow * KB;
    const char* Bbase = Bq + bcol * KB;

    // staging: per chunk c, linear dest dloc = c*8192 + wid*1024 + lane*16;
    // global source = inverse-swizzled logical offset (row*4096 + col).
    int aofs[4];
#pragma unroll
    for (int c = 0; c < 4; ++c) {
        int dloc = c * 8192 + wid * 1024 + lane * 16;
        int l = SWZ(dloc);
        aofs[c] = (l >> 7) * KB + (l & 127);  // same pattern for A and B
    }

    // frag read offsets: col = (kh<<6)|(lh<<5)|(hh<<4), phys = col ^ (row&7)<<4,
    // row&7 == lane&7 for all our rows.
    int cox[4];
#pragma unroll
    for (int kh = 0; kh < 2; ++kh)
#pragma unroll
        for (int hh = 0; hh < 2; ++hh)
            cox[kh * 2 + hh] = (((kh << 6) | (lh << 5) | (hh << 4)) ^ ((lane & 7) << 4));

    int arowb[4], brown[2];
#pragma unroll
    for (int b = 0; b < 4; ++b) arowb[b] = (wr * 128 + b * 32 + l31) << 7;
#pragma unroll
    for (int n = 0; n < 2; ++n) brown[n] = (wc * 64 + n * 32 + l31) << 7;

#define STAGE(kb_, bufb) { \
    _Pragma("unroll") for (int c_ = 0; c_ < 4; ++c_) { \
        char* dA_ = smem + (bufb) * 32768 + c_ * 8192 + wid * 1024; \
        char* dB_ = dA_ + 65536; \
        async16(Abase + aofs[c_] + (kb_) * 128, dA_); \
        async16(Bbase + aofs[c_] + (kb_) * 128, dB_); } \
    if (wid == 0) \
        async16((const char*)AscaleG + ((long)(kb_) * M + brow) * 4 + lane * 16, \
                smem + 131072 + (bufb) * 1024); \
    if (wid == 1) \
        async16((const char*)BscaleG + ((long)(kb_) * N + bcol) * 4 + lane * 16, \
                smem + 133120 + (bufb) * 1024); }

    f32x16 acc[4][2];
#pragma unroll
    for (int b = 0; b < 4; ++b)
#pragma unroll
        for (int n = 0; n < 2; ++n)
#pragma unroll
            for (int e = 0; e < 16; ++e) acc[b][n][e] = 0.f;

    // prologue
    STAGE(0, 0);
    asm volatile("s_waitcnt vmcnt(0)" ::: "memory");
    __builtin_amdgcn_s_barrier();

    for (int kb = 0; kb < 32; ++kb) {
        const int buf = kb & 1;
        if (kb < 31) STAGE(kb + 1, buf ^ 1);

        const char* Ab = smem + buf * 32768;
        const char* Bb = Ab + 65536;
        const float* SaB = (const float*)(smem + 131072 + buf * 1024);
        const float* SbB = (const float*)(smem + 133120 + buf * 1024);

        // B fragments (shared across bands)
        i32x8 b8[2][2];
#pragma unroll
        for (int n = 0; n < 2; ++n)
#pragma unroll
            for (int kh = 0; kh < 2; ++kh)
                b8[n][kh] = mk8(*(const i32x4*)(Bb + brown[n] + cox[kh * 2]),
                                *(const i32x4*)(Bb + brown[n] + cox[kh * 2 + 1]));
        float sbv[2];
#pragma unroll
        for (int n = 0; n < 2; ++n) sbv[n] = SbB[wc * 64 + n * 32 + l31];

        __builtin_amdgcn_s_setprio(1);
#pragma unroll
        for (int b = 0; b < 4; ++b) {
            i32x8 a0 = mk8(*(const i32x4*)(Ab + arowb[b] + cox[0]),
                           *(const i32x4*)(Ab + arowb[b] + cox[1]));
            i32x8 a1 = mk8(*(const i32x4*)(Ab + arowb[b] + cox[2]),
                           *(const i32x4*)(Ab + arowb[b] + cox[3]));
            // row scales: 4 consecutive rows per b128, rows = 32b + 8i + 4*lh
            f32x4 sa4[4];
#pragma unroll
            for (int i = 0; i < 4; ++i)
                sa4[i] = *(const f32x4*)(SaB + wr * 128 + b * 32 + 4 * lh + 8 * i);
#pragma unroll
            for (int n = 0; n < 2; ++n) {
                f32x16 t = __builtin_amdgcn_mfma_scale_f32_32x32x64_f8f6f4(
                    a0, b8[n][0], (f32x16)(0.f), 0, 0, 0, SC1, 0, SC1);
                t = __builtin_amdgcn_mfma_scale_f32_32x32x64_f8f6f4(
                    a1, b8[n][1], t, 0, 0, 0, SC1, 0, SC1);
#pragma unroll
                for (int e = 0; e < 16; ++e)
                    acc[b][n][e] = fmaf(t[e], sa4[e >> 2][e & 3] * sbv[n],
                                        acc[b][n][e]);
            }
        }
        __builtin_amdgcn_s_setprio(0);

        asm volatile("s_waitcnt vmcnt(0)" ::: "memory");
        __builtin_amdgcn_s_barrier();
    }

    // epilogue: 32x32 C/D layout col = lane&31, row = (e&3)+8*(e>>2)+4*(lane>>5)
#pragma unroll
    for (int b = 0; b < 4; ++b)
#pragma unroll
        for (int n = 0; n < 2; ++n)
#pragma unroll
            for (int e = 0; e < 16; ++e) {
                long r = brow + wr * 128 + b * 32 + (e & 3) + 8 * (e >> 2) + 4 * lh;
                long cc = bcol + wc * 64 + n * 32 + l31;
                C[r * (long)N + cc] = acc[b][n][e];
            }
#undef STAGE
}

// ---------------------------------------------------------------------------
extern "C" void kernel_launch(void* const* d_in, const int* in_sizes, int n_in,
                              void* d_out, int out_size, void* d_ws, size_t ws_size,
                              hipStream_t stream) {
    const float* x = (const float*)d_in[0];   // [B,T,D] fp32, M = B*T
    const float* w = (const float*)d_in[1];   // [O,D] fp32
    float* out = (float*)d_out;               // [M,O] fp32

    const int K = 4096;
    const long M = (long)in_sizes[0] / K;     // 8192
    const long N = (long)in_sizes[1] / K;     // 4096

    u16* Aq = (u16*)d_ws;                     // [M][K] fp8 (2/u16) = 32 MB
    u16* Bq = Aq + (size_t)M * K / 2;         // [N][K] fp8 = 16 MB
    float* Asc = (float*)(Bq + (size_t)N * K / 2);  // [32][M] = 1 MB
    float* Bsc = Asc + 32 * (size_t)M;              // [32][N] = 0.5 MB

    const long nblkA = M * 32, nblkB = N * 32;
    quant_kernel<<<dim3((unsigned)((nblkA + 3) / 4)), dim3(256), 0, stream>>>(
        x, Aq, Asc, M);
    quant_kernel<<<dim3((unsigned)((nblkB + 3) / 4)), dim3(256), 0, stream>>>(
        w, Bq, Bsc, N);

    static int smem_set = 0;
    if (!smem_set) {
        hipFuncSetAttribute((const void*)gemm_fp8,
                            hipFuncAttributeMaxDynamicSharedMemorySize, 135168);
        smem_set = 1;
    }
    dim3 grid((unsigned)((M / 256) * (N / 256)));
    gemm_fp8<<<grid, dim3(512), 135168, stream>>>(
        (const char*)Aq, (const char*)Bq, Asc, Bsc, out, (int)M, (int)N);
}